// Round 12
// baseline (41903.156 us; speedup 1.0000x reference)
//
#include <hip/hip_runtime.h>
#include <hip/hip_bf16.h>
#include <stdint.h>

#define TD 128   // decoder steps
#define NB 16    // batch
#define TE 512   // encoder time
#define EE 512   // encoder dim
#define HH 1024  // hidden
#define NM 80    // mel bins
#define PP 256   // prenet dim
#define NWG 256
#define NTH 512

#define AGENT __HIP_MEMORY_SCOPE_AGENT

// mutable cross-WG state: agent-scope relaxed (cache-bypassing, always fresh)
__device__ inline float aloadf(const float* p) {
  return __hip_atomic_load(p, __ATOMIC_RELAXED, AGENT);
}
__device__ inline void astoref(float* p, float v) {
  __hip_atomic_store(p, v, __ATOMIC_RELAXED, AGENT);
}
__device__ inline double aloadd(const double* p) {
  return __hip_atomic_load(p, __ATOMIC_RELAXED, AGENT);
}
__device__ inline void astored(double* p, double v) {
  __hip_atomic_store(p, v, __ATOMIC_RELAXED, AGENT);
}
__device__ inline float2 aload2f(const float* p) {  // 8B-aligned pair
  unsigned long long v =
      __hip_atomic_load((const unsigned long long*)p, __ATOMIC_RELAXED, AGENT);
  union { unsigned long long u; float2 f; } c; c.u = v; return c.f;
}
__device__ inline double dsig(double x) { return 1.0 / (1.0 + exp(-x)); }

// ---------------- Threefry-2x32 (exact JAX schedule) ----------------
__host__ __device__ inline void threefry2x32(uint32_t k0, uint32_t k1,
                                             uint32_t& x0, uint32_t& x1) {
  uint32_t ks0 = k0, ks1 = k1, ks2 = k0 ^ k1 ^ 0x1BD11BDAu;
  x0 += ks0; x1 += ks1;
#define RND(rot) { x0 += x1; x1 = (x1 << (rot)) | (x1 >> (32 - (rot))); x1 ^= x0; }
  RND(13) RND(15) RND(26) RND(6)
  x0 += ks1; x1 += ks2 + 1u;
  RND(17) RND(29) RND(16) RND(24)
  x0 += ks2; x1 += ks0 + 2u;
  RND(13) RND(15) RND(26) RND(6)
  x0 += ks0; x1 += ks1 + 3u;
  RND(17) RND(29) RND(16) RND(24)
  x0 += ks1; x1 += ks2 + 4u;
  RND(13) RND(15) RND(26) RND(6)
  x0 += ks2; x1 += ks0 + 5u;
#undef RND
}

// JAX partitionable threefry random_bits, bit_width=32: bits = out0 ^ out1.
__device__ inline double mask_val(uint32_t ka, uint32_t kb, uint32_t i) {
  uint32_t x0 = 0u, x1 = i;
  threefry2x32(ka, kb, x0, x1);
  uint32_t bits = x0 ^ x1;
  float u = __uint_as_float((bits >> 9) | 0x3f800000u) - 1.0f;
  return (u < 0.5f) ? 2.0 : 0.0;
}

// ---------------- precompute: proc_enc (transposed [b][d][t], fp64->f32) ----------------
__global__ void k_proc_enc(const float* __restrict__ inputs,
                           const float* __restrict__ W_enc,
                           float* __restrict__ procTf) {
  int blk = blockIdx.x;          // 512 = 16 b * 32 t-tiles
  int b = blk >> 5;
  int t0 = (blk & 31) * 16;
  int d = threadIdx.x;           // 128
  __shared__ float in_l[16][EE];
  for (int idx = threadIdx.x; idx < 16 * EE; idx += blockDim.x) {
    int tt = idx >> 9, e = idx & 511;
    in_l[tt][e] = inputs[((size_t)(b * TE + t0 + tt)) * EE + e];
  }
  __syncthreads();
  double acc[16];
#pragma unroll
  for (int tt = 0; tt < 16; ++tt) acc[tt] = 0.0;
  const float* wr = W_enc + (size_t)d * EE;
  for (int e = 0; e < EE; ++e) {
    double w = (double)wr[e];
#pragma unroll
    for (int tt = 0; tt < 16; ++tt) acc[tt] += w * (double)in_l[tt][e];
  }
  for (int tt = 0; tt < 16; ++tt)
    procTf[((size_t)(b * 128 + d)) * TE + t0 + tt] = (float)acc[tt];
}

// ---------------- precompute: prenet p for all (s,b), masks inline ----------------
__global__ void k_p(const float* __restrict__ pm, const float* __restrict__ Wp1,
                    const float* __restrict__ Wp2,
                    uint32_t k1a, uint32_t k1b, uint32_t k2a, uint32_t k2b,
                    float* __restrict__ p_allf) {
  int sb = blockIdx.x;           // s*16+b, 2048 blocks
  int s = sb >> 4, b = sb & 15;
  int tid = threadIdx.x;         // 256
  uint32_t mi = (uint32_t)(sb * PP + tid);
  double d1 = mask_val(k1a, k1b, mi);
  double d2 = mask_val(k2a, k2b, mi);
  __shared__ float x_l[NM];
  __shared__ double p1_l[PP];
  if (tid < NM) x_l[tid] = (s == 0) ? 0.f : pm[(b * NM + tid) * TD + (s - 1)];
  __syncthreads();
  double a = 0.0;
  const float* w1 = Wp1 + tid * NM;
  for (int m = 0; m < NM; ++m) a += (double)w1[m] * (double)x_l[m];
  a = fmax(a, 0.0) * d1;
  p1_l[tid] = a;
  __syncthreads();
  double c = 0.0;
  const float* w2 = Wp2 + tid * PP;
  for (int k = 0; k < PP; ++k) c += (double)w2[k] * p1_l[k];
  c = fmax(c, 0.0) * d2;
  p_allf[sb * PP + tid] = (float)c;
}

// ---------------- init: zero persistent state + barrier memory ----------------
__global__ void k_init(double* __restrict__ cumg, float* __restrict__ ctxf,
                       float* __restrict__ h1f, float* __restrict__ h2f,
                       uint32_t* __restrict__ barmem) {
  int tid = threadIdx.x;
  for (int i = tid; i < NB * TE; i += 256) cumg[i] = 0.0;
  for (int i = tid; i < NB * EE; i += 256) ctxf[i] = 0.f;
  for (int i = tid; i < 2 * HH; i += 256) { h1f[i] = 0.f; h2f[i] = 0.f; }
  for (int i = tid; i < 8192; i += 256) barmem[i] = 0u;
}

// ---------------- persistent LDS layout ----------------
struct SMEM {
  float wldT[4096];            // wldT[c*128+d] = W_ld[d*32+c]
  float wcl[992];
  double bld[128], we[128], blc[32];
  double b1l[16], b2l[16];
  double g1l[16][16];          // g1pre per item per owned-row
  double gA[16], gBC[16];
  double c1l[4], c2l[4];
  double be0;
  union U {
    struct { float h1[1024], h2[1024]; } cell;                          // 8 KB
    struct { float ctxall[8192]; } g1p;                                  // 32 KB
    struct { float h[1024]; double cum[64], q[128], loc[32][33]; } att;  // ~14 KB
    struct { float aw[512]; double red[16][32]; double red8[8]; } ctxp;  // ~6.2 KB
    struct { float hb[1536]; double red[16]; } outp;                     // 6.3 KB
  } u;
};

// Fully replicated-flag barrier (no shared polled line anywhere):
//  - WG w (w>0) leader STORES lgen to its private arrival line barmem[w*16]
//  - WG0 threads 256..510 poll the 255 arrival lines in parallel
//  - WG0 threads 0..255 then STORE lgen to 256 private release lines
//  - each WG w polls ONLY its own release line barmem[4096 + w*16].
// Monotonic generations -> no reset phase. Visibility: __syncthreads drains
// each wave's vmem (data acked at coherence point) before any flag store.
__device__ inline void gridbar(uint32_t* barmem, uint32_t& lgen, int wg, int tid) {
  __syncthreads();
  lgen++;
  if (wg == 0) {
    if (tid >= 256 && tid < 511) {
      const uint32_t* fl = &barmem[(tid - 255) * 16];
      while (__hip_atomic_load(fl, __ATOMIC_RELAXED, AGENT) < lgen)
        __builtin_amdgcn_s_sleep(1);
    }
    __syncthreads();
    if (tid < 256) {
      asm volatile("s_waitcnt vmcnt(0)" ::: "memory");
      __hip_atomic_store(&barmem[4096 + tid * 16], lgen, __ATOMIC_RELAXED, AGENT);
    }
  } else {
    if (tid == 0) {
      __hip_atomic_store(&barmem[wg * 16], lgen, __ATOMIC_RELAXED, AGENT);
      while (__hip_atomic_load(&barmem[4096 + wg * 16], __ATOMIC_RELAXED, AGENT) < lgen)
        __builtin_amdgcn_s_sleep(1);
    }
  }
  __syncthreads();
}

// ---------------- the persistent decoder kernel ----------------
__global__ __launch_bounds__(NTH)
__attribute__((amdgpu_waves_per_eu(2, 2)))
void k_persist(
    const float* __restrict__ inputs,
    const float* __restrict__ W_q,
    const float* __restrict__ W_lc, const float* __restrict__ b_lc,
    const float* __restrict__ W_ld, const float* __restrict__ b_ld,
    const float* __restrict__ w_e, const float* __restrict__ b_e,
    const float* __restrict__ W_ih1, const float* __restrict__ W_hh1,
    const float* __restrict__ b_ih1, const float* __restrict__ b_hh1,
    const float* __restrict__ W_ih2, const float* __restrict__ W_hh2,
    const float* __restrict__ b_ih2, const float* __restrict__ b_hh2,
    const float* __restrict__ W_proj, const float* __restrict__ b_proj,
    const float* __restrict__ W_stop, const float* __restrict__ b_stop,
    const float* __restrict__ p_allf, const float* __restrict__ procTf,
    float* h1f, float* h2f, float* h_allf,
    float* ef, double* cumg, float* ctxf,
    uint32_t* barmem, float* out) {
  __shared__ SMEM sm;
  const int wg = blockIdx.x, tid = threadIdx.x;
  const int q = tid >> 5, l = tid & 31;       // row-slot 0..15, col-lane 0..31
  const int row = (q >> 2) * 1024 + wg * 4 + (q & 3);  // owned row in 4096
  uint32_t lgen = 0;

  // ---- persistent LDS constants ----
  for (int i = tid; i < 4096; i += NTH) sm.wldT[(i & 31) * 128 + (i >> 5)] = W_ld[i];
  for (int i = tid; i < 992; i += NTH) sm.wcl[i] = W_lc[i];
  for (int i = tid; i < 128; i += NTH) { sm.bld[i] = (double)b_ld[i]; sm.we[i] = (double)w_e[i]; }
  if (tid < 32) sm.blc[tid] = (double)b_lc[tid];
  if (tid == 0) sm.be0 = (double)b_e[0];
  if (l == 0) {
    sm.b1l[q] = (double)b_ih1[row] + (double)b_hh1[row];
    sm.b2l[q] = (double)b_ih2[row] + (double)b_hh2[row];
  }

  // ---- register-resident weights (120 regs, pinned) ----
  float wA[32], wB[32], wC[32], wD[24];
#pragma unroll
  for (int k = 0; k < 32; ++k) {
    int c = l + 32 * k;
    wA[k] = W_hh1[(size_t)row * 1024 + c];
    wB[k] = W_ih2[(size_t)row * 1024 + c];
    wC[k] = W_hh2[(size_t)row * 1024 + c];
  }
#pragma unroll
  for (int k = 0; k < 24; ++k) wD[k] = W_ih1[(size_t)row * 768 + l + 32 * k];
#pragma unroll
  for (int k = 0; k < 32; ++k) {
    asm volatile("" : "+v"(wA[k]));
    asm volatile("" : "+v"(wB[k]));
    asm volatile("" : "+v"(wC[k]));
  }
#pragma unroll
  for (int k = 0; k < 24; ++k) asm volatile("" : "+v"(wD[k]));
  __syncthreads();

  // ---- prologue: g1pre for step 0 (ctx zeroed by k_init) ----
  {
    for (int i = tid; i < 8192; i += NTH) sm.u.g1p.ctxall[i] = aloadf(ctxf + i);
    __syncthreads();
    for (int b = 0; b < 16; ++b) {
      double a = 0.0;
#pragma unroll
      for (int k = 0; k < 8; ++k)
        a += (double)wD[k] * (double)p_allf[((size_t)0 * 16 + b) * 256 + l + 32 * k];
#pragma unroll
      for (int k = 8; k < 24; ++k)
        a += (double)wD[k] * (double)sm.u.g1p.ctxall[b * 512 + l + 32 * k - 256];
#pragma unroll
      for (int m = 1; m <= 16; m <<= 1) a += __shfl_xor(a, m);
      if (l == 0) sm.g1l[b][q] = a + sm.b1l[q];
    }
    __syncthreads();
  }
  gridbar(barmem, lgen, wg, tid);

  for (int s = 0; s < TD; ++s) {
    // ================= 17 pipelined cell rounds =================
    for (int r = 0; r <= 16; ++r) {
      if (r == 0 && tid < 4) { sm.c1l[tid] = 0.0; sm.c2l[tid] = 0.0; }
      {
        float2 v1 = aload2f(h1f + (((r & 1) ^ 1)) * 1024 + 2 * tid);
        sm.u.cell.h1[2 * tid] = v1.x; sm.u.cell.h1[2 * tid + 1] = v1.y;
        if (r > 0) {
          float2 v2 = aload2f(h2f + (r & 1) * 1024 + 2 * tid);
          sm.u.cell.h2[2 * tid] = v2.x; sm.u.cell.h2[2 * tid + 1] = v2.y;
        }
      }
      __syncthreads();

      double a0 = 0.0, a1 = 0.0, a2 = 0.0;
#pragma unroll
      for (int k = 0; k < 32; ++k) {
        double h1v = (double)sm.u.cell.h1[l + 32 * k];
        a0 += (double)wA[k] * h1v;
        a1 += (double)wB[k] * h1v;
        a2 += (double)wC[k] * (double)sm.u.cell.h2[l + 32 * k];
      }
#pragma unroll
      for (int m = 1; m <= 16; m <<= 1) {
        a0 += __shfl_xor(a0, m);
        a1 += __shfl_xor(a1, m);
        a2 += __shfl_xor(a2, m);
      }
      if (l == 0) { sm.gA[q] = a0; sm.gBC[q] = a1 + a2; }
      __syncthreads();

      if (r < 16 && tid < 4) {          // cell1(item r)
        int jj = tid;
        double gi = sm.g1l[r][jj]      + sm.gA[jj];
        double gf = sm.g1l[r][4 + jj]  + sm.gA[4 + jj];
        double gg = sm.g1l[r][8 + jj]  + sm.gA[8 + jj];
        double go = sm.g1l[r][12 + jj] + sm.gA[12 + jj];
        double cn = dsig(gf) * sm.c1l[jj] + dsig(gi) * tanh(gg);
        double hn = dsig(go) * tanh(cn);
        sm.c1l[jj] = cn;
        astoref(h1f + (r & 1) * 1024 + wg * 4 + jj, (float)hn);
      }
      if (r > 0 && tid >= 8 && tid < 12) {  // cell2(item r-1)
        int jj = tid - 8, b = r - 1;
        double gi = sm.gBC[jj]      + sm.b2l[jj];
        double gf = sm.gBC[4 + jj]  + sm.b2l[4 + jj];
        double gg = sm.gBC[8 + jj]  + sm.b2l[8 + jj];
        double go = sm.gBC[12 + jj] + sm.b2l[12 + jj];
        double cn = dsig(gf) * sm.c2l[jj] + dsig(gi) * tanh(gg);
        double hn = dsig(go) * tanh(cn);
        sm.c2l[jj] = cn;
        astoref(h2f + ((b & 1)) * 1024 + wg * 4 + jj, (float)hn);
        astoref(h_allf + (size_t)b * 1024 + wg * 4 + jj, (float)hn);
      }
      gridbar(barmem, lgen, wg, tid);
    }

    // ================= P_att : q (local, fp64) + energies =================
    {
      int b = wg >> 4, t0 = (wg & 15) * 32;
      {
        float2 v = aload2f(h_allf + (size_t)b * 1024 + 2 * tid);
        sm.u.att.h[2 * tid] = v.x; sm.u.att.h[2 * tid + 1] = v.y;
      }
      if (tid < 62) {
        int g = t0 - 15 + tid;
        sm.u.att.cum[tid] = (g >= 0 && g < TE) ? aloadd(cumg + b * TE + g) : 0.0;
      }
      __syncthreads();
      {  // q[d] = W_q[d] . h  (d = tid>>2, 4 threads x 256 cols)
        int d = tid >> 2, sub = tid & 3;
        const float* wq = W_q + (size_t)d * 1024 + sub * 256;
        const float* hh = sm.u.att.h + sub * 256;
        double a = 0.0;
        for (int k = 0; k < 256; ++k) a += (double)wq[k] * (double)hh[k];
        a += __shfl_xor(a, 1); a += __shfl_xor(a, 2);
        if (sub == 0) sm.u.att.q[d] = a;
      }
#pragma unroll
      for (int it = 0; it < 2; ++it) {   // conv loc
        int task = tid + it * NTH;
        int t = task >> 5, ch = task & 31;
        double v = sm.blc[ch];
#pragma unroll
        for (int k = 0; k < 31; ++k) v += (double)sm.wcl[ch * 31 + k] * sm.u.att.cum[t + k];
        sm.u.att.loc[t][ch] = v;
      }
      __syncthreads();
      int t = tid >> 4, part = tid & 15;
      double en = 0.0;
      for (int k = 0; k < 8; ++k) {
        int d = part + 16 * k;
        double sv = sm.u.att.q[d] + sm.bld[d] +
                    (double)procTf[((size_t)(b * 128 + d)) * TE + t0 + t];
#pragma unroll
        for (int c = 0; c < 32; ++c)
          sv += sm.u.att.loc[t][c] * (double)sm.wldT[c * 128 + d];
        en += tanh(sv) * sm.we[d];
      }
#pragma unroll
      for (int m = 1; m <= 8; m <<= 1) en += __shfl_xor(en, m);
      if (part == 0) astoref(ef + b * TE + t0 + t, (float)(en + sm.be0));
    }
    gridbar(barmem, lgen, wg, tid);

    // ================= P_ctx : softmax (redundant x16) + ctx + cum =================
    {
      int b = wg >> 4, e0 = (wg & 15) * 32;
      double e = (double)aloadf(ef + b * TE + tid);
      double mx = e;
#pragma unroll
      for (int m = 1; m <= 32; m <<= 1) mx = fmax(mx, __shfl_xor(mx, m));
      if ((tid & 63) == 0) sm.u.ctxp.red8[tid >> 6] = mx;
      __syncthreads();
      if (tid == 0) {
        double mm = sm.u.ctxp.red8[0];
        for (int i = 1; i < 8; ++i) mm = fmax(mm, sm.u.ctxp.red8[i]);
        sm.u.ctxp.red8[0] = mm;
      }
      __syncthreads();
      double p = exp(e - sm.u.ctxp.red8[0]);
      __syncthreads();
      double ssum = p;
#pragma unroll
      for (int m = 1; m <= 32; m <<= 1) ssum += __shfl_xor(ssum, m);
      if ((tid & 63) == 0) sm.u.ctxp.red8[tid >> 6] = ssum;
      __syncthreads();
      if (tid == 0) {
        double t_ = 0.0;
        for (int i = 0; i < 8; ++i) t_ += sm.u.ctxp.red8[i];
        sm.u.ctxp.red8[0] = 1.0 / t_;
      }
      __syncthreads();
      double a = p * sm.u.ctxp.red8[0];
      sm.u.ctxp.aw[tid] = (float)a;                    // f32 aw (as before)
      if ((wg & 15) == 0)                              // designated cum writer
        astored(cumg + b * TE + tid, aloadd(cumg + b * TE + tid) + a);
      __syncthreads();
      int e2 = e0 + (tid & 31), tp = tid >> 5;
      double acc = 0.0;
      for (int t = tp * 32; t < tp * 32 + 32; ++t)
        acc += (double)sm.u.ctxp.aw[t] * (double)inputs[((size_t)(b * TE + t)) * EE + e2];
      sm.u.ctxp.red[tp][tid & 31] = acc;
      __syncthreads();
      if (tid < 32) {
        double v = 0.0;
        for (int j = 0; j < 16; ++j) v += sm.u.ctxp.red[j][tid];
        astoref(ctxf + b * EE + e0 + tid, (float)v);
      }
    }
    gridbar(barmem, lgen, wg, tid);

    // ================= P_out (fixed b per WG) + g1pre(s+1) =================
    {
      int b = wg & 15, obase = wg >> 4;
      for (int i = tid; i < 1536; i += NTH)
        sm.u.outp.hb[i] = (i < 1024) ? aloadf(h_allf + (size_t)b * 1024 + i)
                                     : aloadf(ctxf + b * EE + (i - 1024));
      __syncthreads();
      for (int j = 0; j < 6; ++j) {
        int o = obase + 16 * j;      // 0..95; valid when o <= 80
        if (o <= NM) {
          const float* wr = (o < NM) ? (W_proj + (size_t)o * 1536) : W_stop;
          double a = 0.0;
#pragma unroll
          for (int kk = 0; kk < 3; ++kk) {
            int k = tid + kk * NTH;
            a += (double)wr[k] * (double)sm.u.outp.hb[k];
          }
#pragma unroll
          for (int m = 1; m <= 32; m <<= 1) a += __shfl_xor(a, m);
          if ((tid & 63) == 0) sm.u.outp.red[tid >> 6] = a;
          __syncthreads();
          if (tid == 0) {
            double v = 0.0;
            for (int i = 0; i < 8; ++i) v += sm.u.outp.red[i];
            v += (o < NM) ? (double)b_proj[o] : (double)b_stop[0];
            if (o < NM) out[((size_t)b * TD + s) * NM + o] = (float)v;
            else        out[(size_t)NB * TD * NM + b * TD + s] = (float)v;
          }
          __syncthreads();
        }
      }
      __syncthreads();
      if (s < TD - 1) {
        const int ss = s + 1;
        for (int i = tid; i < 8192; i += NTH) sm.u.g1p.ctxall[i] = aloadf(ctxf + i);
        __syncthreads();
        for (int b2 = 0; b2 < 16; ++b2) {
          double a = 0.0;
#pragma unroll
          for (int k = 0; k < 8; ++k)
            a += (double)wD[k] * (double)p_allf[((size_t)ss * 16 + b2) * 256 + l + 32 * k];
#pragma unroll
          for (int k = 8; k < 24; ++k)
            a += (double)wD[k] * (double)sm.u.g1p.ctxall[b2 * 512 + l + 32 * k - 256];
#pragma unroll
          for (int m = 1; m <= 16; m <<= 1) a += __shfl_xor(a, m);
          if (l == 0) sm.g1l[b2][q] = a + sm.b1l[q];
        }
        __syncthreads();
        if (tid < 4) astoref(h1f + 1024 + wg * 4 + tid, 0.f);
        else if (tid < 8) astoref(h2f + 1024 + wg * 4 + (tid - 4), 0.f);
      }
    }
    gridbar(barmem, lgen, wg, tid);
  }
}

extern "C" void kernel_launch(void* const* d_in, const int* in_sizes, int n_in,
                              void* d_out, int out_size, void* d_ws, size_t ws_size,
                              hipStream_t stream) {
  const float* inputs = (const float*)d_in[0];
  const float* pmels  = (const float*)d_in[1];
  const float* W_enc  = (const float*)d_in[2];
  const float* W_q    = (const float*)d_in[3];
  const float* W_lc   = (const float*)d_in[4];
  const float* b_lc   = (const float*)d_in[5];
  const float* W_ld   = (const float*)d_in[6];
  const float* b_ld   = (const float*)d_in[7];
  const float* w_e    = (const float*)d_in[8];
  const float* b_e    = (const float*)d_in[9];
  const float* W_p1   = (const float*)d_in[10];
  const float* W_p2   = (const float*)d_in[11];
  const float* W_ih1  = (const float*)d_in[12];
  const float* W_hh1  = (const float*)d_in[13];
  const float* b_ih1  = (const float*)d_in[14];
  const float* b_hh1  = (const float*)d_in[15];
  const float* W_ih2  = (const float*)d_in[16];
  const float* W_hh2  = (const float*)d_in[17];
  const float* b_ih2  = (const float*)d_in[18];
  const float* b_hh2  = (const float*)d_in[19];
  const float* W_proj = (const float*)d_in[20];
  const float* b_proj = (const float*)d_in[21];
  const float* W_stop = (const float*)d_in[22];
  const float* b_stop = (const float*)d_in[23];
  float* out = (float*)d_out;

  float* ws     = (float*)d_ws;
  float* p_allf = ws;                   // 524288 f
  float* procTf = p_allf + 524288;      // 1048576 f
  float* h1f    = procTf + 1048576;     // 2048 f (2 parity slots)
  float* h2f    = h1f + 2048;           // 2048 f
  float* h_allf = h2f + 2048;           // 16384 f
  float* ef     = h_allf + 16384;       // 8192 f
  float* ctxf   = ef + 8192;            // 8192 f
  double* cumg  = (double*)(ctxf + 8192);        // 8192 d
  uint32_t* barmem = (uint32_t*)(cumg + 8192);   // 8192 u32 (flags + releases)

  // fold_in keys on host: key(42) = (0,42); fold_in data 0 / 1
  uint32_t k1a = 0u, k1b = 0u, k2a = 0u, k2b = 1u;
  threefry2x32(0u, 42u, k1a, k1b);
  threefry2x32(0u, 42u, k2a, k2b);

  k_proc_enc<<<512, 128, 0, stream>>>(inputs, W_enc, procTf);
  k_p<<<TD * NB, 256, 0, stream>>>(pmels, W_p1, W_p2, k1a, k1b, k2a, k2b, p_allf);
  k_init<<<1, 256, 0, stream>>>(cumg, ctxf, h1f, h2f, barmem);

  k_persist<<<NWG, NTH, 0, stream>>>(
      inputs, W_q, W_lc, b_lc, W_ld, b_ld, w_e, b_e,
      W_ih1, W_hh1, b_ih1, b_hh1, W_ih2, W_hh2, b_ih2, b_hh2,
      W_proj, b_proj, W_stop, b_stop,
      p_allf, procTf, h1f, h2f, h_allf, ef, cumg, ctxf,
      barmem, out);

  (void)in_sizes; (void)n_in; (void)out_size; (void)ws_size;
}

// Round 13
// 33798.953 us; speedup vs baseline: 1.2398x; 1.2398x over previous
//
#include <hip/hip_runtime.h>
#include <hip/hip_bf16.h>
#include <stdint.h>

#define TD 128   // decoder steps
#define NB 16    // batch
#define TE 512   // encoder time
#define EE 512   // encoder dim
#define HH 1024  // hidden
#define NM 80    // mel bins
#define PP 256   // prenet dim
#define NWG 256
#define NTH 512

#define AGENT __HIP_MEMORY_SCOPE_AGENT

typedef float f32x4 __attribute__((ext_vector_type(4)));

// ---- WRITE path: agent-scope relaxed (sc0+sc1 write-through to MALL) ----
__device__ inline void astoref(float* p, float v) {
  __hip_atomic_store(p, v, __ATOMIC_RELAXED, AGENT);
}
__device__ inline void astored(double* p, double v) {
  __hip_atomic_store(p, v, __ATOMIC_RELAXED, AGENT);
}
// ---- READ path: sc0-only loads — L1 bypass, L2 HIT ALLOWED.            ----
// Freshness: every WG does one agent-acquire (L1+L2 inv) pre-arrival in
// gridbar, so any L2 line alive after the release is post-invalidate fresh.
__device__ inline f32x4 ntload4(const float* p) {
  f32x4 r;
  asm volatile("global_load_dwordx4 %0, %1, off sc0\n\ts_waitcnt vmcnt(0)"
               : "=&v"(r) : "v"(p) : "memory");
  return r;
}
__device__ inline float ntload1f(const float* p) {
  float r;
  asm volatile("global_load_dword %0, %1, off sc0\n\ts_waitcnt vmcnt(0)"
               : "=&v"(r) : "v"(p) : "memory");
  return r;
}
__device__ inline double ntload1d(const double* p) {
  double r;
  asm volatile("global_load_dwordx2 %0, %1, off sc0\n\ts_waitcnt vmcnt(0)"
               : "=&v"(r) : "v"(p) : "memory");
  return r;
}
__device__ inline double dsig(double x) { return 1.0 / (1.0 + exp(-x)); }

// ---------------- Threefry-2x32 (exact JAX schedule) ----------------
__host__ __device__ inline void threefry2x32(uint32_t k0, uint32_t k1,
                                             uint32_t& x0, uint32_t& x1) {
  uint32_t ks0 = k0, ks1 = k1, ks2 = k0 ^ k1 ^ 0x1BD11BDAu;
  x0 += ks0; x1 += ks1;
#define RND(rot) { x0 += x1; x1 = (x1 << (rot)) | (x1 >> (32 - (rot))); x1 ^= x0; }
  RND(13) RND(15) RND(26) RND(6)
  x0 += ks1; x1 += ks2 + 1u;
  RND(17) RND(29) RND(16) RND(24)
  x0 += ks2; x1 += ks0 + 2u;
  RND(13) RND(15) RND(26) RND(6)
  x0 += ks0; x1 += ks1 + 3u;
  RND(17) RND(29) RND(16) RND(24)
  x0 += ks1; x1 += ks2 + 4u;
  RND(13) RND(15) RND(26) RND(6)
  x0 += ks2; x1 += ks0 + 5u;
#undef RND
}

// JAX partitionable threefry random_bits, bit_width=32: bits = out0 ^ out1.
__device__ inline double mask_val(uint32_t ka, uint32_t kb, uint32_t i) {
  uint32_t x0 = 0u, x1 = i;
  threefry2x32(ka, kb, x0, x1);
  uint32_t bits = x0 ^ x1;
  float u = __uint_as_float((bits >> 9) | 0x3f800000u) - 1.0f;
  return (u < 0.5f) ? 2.0 : 0.0;
}

// ---------------- precompute: proc_enc (transposed [b][d][t], fp64->f32) ----------------
__global__ void k_proc_enc(const float* __restrict__ inputs,
                           const float* __restrict__ W_enc,
                           float* __restrict__ procTf) {
  int blk = blockIdx.x;          // 512 = 16 b * 32 t-tiles
  int b = blk >> 5;
  int t0 = (blk & 31) * 16;
  int d = threadIdx.x;           // 128
  __shared__ float in_l[16][EE];
  for (int idx = threadIdx.x; idx < 16 * EE; idx += blockDim.x) {
    int tt = idx >> 9, e = idx & 511;
    in_l[tt][e] = inputs[((size_t)(b * TE + t0 + tt)) * EE + e];
  }
  __syncthreads();
  double acc[16];
#pragma unroll
  for (int tt = 0; tt < 16; ++tt) acc[tt] = 0.0;
  const float* wr = W_enc + (size_t)d * EE;
  for (int e = 0; e < EE; ++e) {
    double w = (double)wr[e];
#pragma unroll
    for (int tt = 0; tt < 16; ++tt) acc[tt] += w * (double)in_l[tt][e];
  }
  for (int tt = 0; tt < 16; ++tt)
    procTf[((size_t)(b * 128 + d)) * TE + t0 + tt] = (float)acc[tt];
}

// ---------------- precompute: prenet p for all (s,b), masks inline ----------------
__global__ void k_p(const float* __restrict__ pm, const float* __restrict__ Wp1,
                    const float* __restrict__ Wp2,
                    uint32_t k1a, uint32_t k1b, uint32_t k2a, uint32_t k2b,
                    float* __restrict__ p_allf) {
  int sb = blockIdx.x;           // s*16+b, 2048 blocks
  int s = sb >> 4, b = sb & 15;
  int tid = threadIdx.x;         // 256
  uint32_t mi = (uint32_t)(sb * PP + tid);
  double d1 = mask_val(k1a, k1b, mi);
  double d2 = mask_val(k2a, k2b, mi);
  __shared__ float x_l[NM];
  __shared__ double p1_l[PP];
  if (tid < NM) x_l[tid] = (s == 0) ? 0.f : pm[(b * NM + tid) * TD + (s - 1)];
  __syncthreads();
  double a = 0.0;
  const float* w1 = Wp1 + tid * NM;
  for (int m = 0; m < NM; ++m) a += (double)w1[m] * (double)x_l[m];
  a = fmax(a, 0.0) * d1;
  p1_l[tid] = a;
  __syncthreads();
  double c = 0.0;
  const float* w2 = Wp2 + tid * PP;
  for (int k = 0; k < PP; ++k) c += (double)w2[k] * p1_l[k];
  c = fmax(c, 0.0) * d2;
  p_allf[sb * PP + tid] = (float)c;
}

// ---------------- init: zero persistent state + barrier memory ----------------
__global__ void k_init(double* __restrict__ cumg, float* __restrict__ ctxf,
                       float* __restrict__ h1f, float* __restrict__ h2f,
                       uint32_t* __restrict__ barmem) {
  int tid = threadIdx.x;
  for (int i = tid; i < NB * TE; i += 256) cumg[i] = 0.0;
  for (int i = tid; i < NB * EE; i += 256) ctxf[i] = 0.f;
  for (int i = tid; i < 2 * HH; i += 256) { h1f[i] = 0.f; h2f[i] = 0.f; }
  for (int i = tid; i < 8192; i += 256) barmem[i] = 0u;
}

// ---------------- persistent LDS layout ----------------
struct SMEM {
  float wldT[4096];            // wldT[c*128+d] = W_ld[d*32+c]
  float wcl[992];
  double bld[128], we[128], blc[32];
  double b1l[16], b2l[16];
  double g1l[16][16];          // g1pre per item per owned-row
  double gA[16], gBC[16];
  double c1l[4], c2l[4];
  double be0;
  union U {
    struct { float h1[1024], h2[1024]; } cell;            // 8 KB
    struct { float h[1024]; } pq;                          // 4 KB
    struct { float ctxall[8192]; } g1p;                    // 32 KB
    struct { double cum[64], q[128], loc[32][33]; } att;   // ~14 KB
    struct { float aw[512]; double red[16][32]; } ctxp;    // 6.1 KB
    struct { double red[16]; } soft;
    struct { float hb[1536]; double red[16]; } outp;       // 6.3 KB
  } u;
};

// Replicated-flag barrier + pre-arrival cache invalidate:
//  - each WG leader: agent-ACQUIRE (L1+L2 inv) -> arrival store -> poll own
//    private release line. All invs complete before release fires, so they
//    never evict post-release L2 fills.
//  - WG0 threads 256..510 poll the 255 arrival lines in parallel; threads
//    0..255 store 256 private release lines.
__device__ inline void gridbar(uint32_t* barmem, uint32_t& lgen, int wg, int tid) {
  __syncthreads();
  lgen++;
  if (wg == 0) {
    if (tid == 0)
      (void)__hip_atomic_load(&barmem[0], __ATOMIC_ACQUIRE, AGENT);  // inv
    if (tid >= 256 && tid < 511) {
      const uint32_t* fl = &barmem[(tid - 255) * 16];
      while (__hip_atomic_load(fl, __ATOMIC_RELAXED, AGENT) < lgen)
        __builtin_amdgcn_s_sleep(1);
    }
    __syncthreads();
    if (tid < 256) {
      asm volatile("s_waitcnt vmcnt(0)" ::: "memory");
      __hip_atomic_store(&barmem[4096 + tid * 16], lgen, __ATOMIC_RELAXED, AGENT);
    }
  } else {
    if (tid == 0) {
      (void)__hip_atomic_load(&barmem[wg * 16], __ATOMIC_ACQUIRE, AGENT);  // inv
      __hip_atomic_store(&barmem[wg * 16], lgen, __ATOMIC_RELAXED, AGENT);
      while (__hip_atomic_load(&barmem[4096 + wg * 16], __ATOMIC_RELAXED, AGENT) < lgen)
        __builtin_amdgcn_s_sleep(1);
    }
  }
  __syncthreads();
}

// ---------------- the persistent decoder kernel ----------------
__global__ __launch_bounds__(NTH)
__attribute__((amdgpu_waves_per_eu(2, 2)))
void k_persist(
    const float* __restrict__ inputs,
    const float* __restrict__ W_q,
    const float* __restrict__ W_lc, const float* __restrict__ b_lc,
    const float* __restrict__ W_ld, const float* __restrict__ b_ld,
    const float* __restrict__ w_e, const float* __restrict__ b_e,
    const float* __restrict__ W_ih1, const float* __restrict__ W_hh1,
    const float* __restrict__ b_ih1, const float* __restrict__ b_hh1,
    const float* __restrict__ W_ih2, const float* __restrict__ W_hh2,
    const float* __restrict__ b_ih2, const float* __restrict__ b_hh2,
    const float* __restrict__ W_proj, const float* __restrict__ b_proj,
    const float* __restrict__ W_stop, const float* __restrict__ b_stop,
    const float* __restrict__ p_allf, const float* __restrict__ procTf,
    float* h1f, float* h2f, float* h_allf, float* qf,
    float* ef, float* awf, double* cumg, float* ctxf,
    uint32_t* barmem, float* out) {
  __shared__ SMEM sm;
  const int wg = blockIdx.x, tid = threadIdx.x;
  const int q = tid >> 5, l = tid & 31;       // row-slot 0..15, col-lane 0..31
  const int row = (q >> 2) * 1024 + wg * 4 + (q & 3);  // owned row in 4096
  uint32_t lgen = 0;

  // ---- persistent LDS constants ----
  for (int i = tid; i < 4096; i += NTH) sm.wldT[(i & 31) * 128 + (i >> 5)] = W_ld[i];
  for (int i = tid; i < 992; i += NTH) sm.wcl[i] = W_lc[i];
  for (int i = tid; i < 128; i += NTH) { sm.bld[i] = (double)b_ld[i]; sm.we[i] = (double)w_e[i]; }
  if (tid < 32) sm.blc[tid] = (double)b_lc[tid];
  if (tid == 0) sm.be0 = (double)b_e[0];
  if (l == 0) {
    sm.b1l[q] = (double)b_ih1[row] + (double)b_hh1[row];
    sm.b2l[q] = (double)b_ih2[row] + (double)b_hh2[row];
  }

  // ---- register-resident weights (120 regs, pinned) ----
  float wA[32], wB[32], wC[32], wD[24];
#pragma unroll
  for (int k = 0; k < 32; ++k) {
    int c = l + 32 * k;
    wA[k] = W_hh1[(size_t)row * 1024 + c];
    wB[k] = W_ih2[(size_t)row * 1024 + c];
    wC[k] = W_hh2[(size_t)row * 1024 + c];
  }
#pragma unroll
  for (int k = 0; k < 24; ++k) wD[k] = W_ih1[(size_t)row * 768 + l + 32 * k];
#pragma unroll
  for (int k = 0; k < 32; ++k) {
    asm volatile("" : "+v"(wA[k]));
    asm volatile("" : "+v"(wB[k]));
    asm volatile("" : "+v"(wC[k]));
  }
#pragma unroll
  for (int k = 0; k < 24; ++k) asm volatile("" : "+v"(wD[k]));
  __syncthreads();

  // ---- prologue: g1pre for step 0 (ctx zeroed by k_init) ----
  {
    for (int j = 0; j < 4; ++j) {
      f32x4 v = ntload4(ctxf + (tid + j * NTH) * 4);
      *(f32x4*)&sm.u.g1p.ctxall[(tid + j * NTH) * 4] = v;
    }
    __syncthreads();
    for (int b = 0; b < 16; ++b) {
      double a = 0.0;
#pragma unroll
      for (int k = 0; k < 8; ++k)
        a += (double)wD[k] * (double)p_allf[((size_t)0 * 16 + b) * 256 + l + 32 * k];
#pragma unroll
      for (int k = 8; k < 24; ++k)
        a += (double)wD[k] * (double)sm.u.g1p.ctxall[b * 512 + l + 32 * k - 256];
#pragma unroll
      for (int m = 1; m <= 16; m <<= 1) a += __shfl_xor(a, m);
      if (l == 0) sm.g1l[b][q] = a + sm.b1l[q];
    }
    __syncthreads();
  }
  gridbar(barmem, lgen, wg, tid);

  for (int s = 0; s < TD; ++s) {
    // ================= 17 pipelined cell rounds =================
    for (int r = 0; r <= 16; ++r) {
      if (r == 0 && tid < 4) { sm.c1l[tid] = 0.0; sm.c2l[tid] = 0.0; }
      // stage h1(r-1) [slot (r&1)^1] and h2(r-2) [slot r&1] via sc0 loads
      if (tid < 256) {
        f32x4 v = ntload4(h1f + (((r & 1) ^ 1)) * 1024 + tid * 4);
        *(f32x4*)&sm.u.cell.h1[tid * 4] = v;
      } else if (r > 0) {
        f32x4 v = ntload4(h2f + (r & 1) * 1024 + (tid - 256) * 4);
        *(f32x4*)&sm.u.cell.h2[(tid - 256) * 4] = v;
      }
      __syncthreads();

      double a0 = 0.0, a1 = 0.0, a2 = 0.0;
#pragma unroll
      for (int k = 0; k < 32; ++k) {
        double h1v = (double)sm.u.cell.h1[l + 32 * k];
        a0 += (double)wA[k] * h1v;
        a1 += (double)wB[k] * h1v;
        a2 += (double)wC[k] * (double)sm.u.cell.h2[l + 32 * k];
      }
#pragma unroll
      for (int m = 1; m <= 16; m <<= 1) {
        a0 += __shfl_xor(a0, m);
        a1 += __shfl_xor(a1, m);
        a2 += __shfl_xor(a2, m);
      }
      if (l == 0) { sm.gA[q] = a0; sm.gBC[q] = a1 + a2; }
      __syncthreads();

      if (r < 16 && tid < 4) {          // cell1(item r)
        int jj = tid;
        double gi = sm.g1l[r][jj]      + sm.gA[jj];
        double gf = sm.g1l[r][4 + jj]  + sm.gA[4 + jj];
        double gg = sm.g1l[r][8 + jj]  + sm.gA[8 + jj];
        double go = sm.g1l[r][12 + jj] + sm.gA[12 + jj];
        double cn = dsig(gf) * sm.c1l[jj] + dsig(gi) * tanh(gg);
        double hn = dsig(go) * tanh(cn);
        sm.c1l[jj] = cn;
        astoref(h1f + (r & 1) * 1024 + wg * 4 + jj, (float)hn);
      }
      if (r > 0 && tid >= 8 && tid < 12) {  // cell2(item r-1)
        int jj = tid - 8, b = r - 1;
        double gi = sm.gBC[jj]      + sm.b2l[jj];
        double gf = sm.gBC[4 + jj]  + sm.b2l[4 + jj];
        double gg = sm.gBC[8 + jj]  + sm.b2l[8 + jj];
        double go = sm.gBC[12 + jj] + sm.b2l[12 + jj];
        double cn = dsig(gf) * sm.c2l[jj] + dsig(gi) * tanh(gg);
        double hn = dsig(go) * tanh(cn);
        sm.c2l[jj] = cn;
        astoref(h2f + ((b & 1)) * 1024 + wg * 4 + jj, (float)hn);
        astoref(h_allf + (size_t)b * 1024 + wg * 4 + jj, (float)hn);
      }
      gridbar(barmem, lgen, wg, tid);
    }

    // ================= P_q : q[b][d] = Wq . h_all[b] =================
    {
      int b = wg >> 4;
      if (tid < 256) {
        f32x4 v = ntload4(h_allf + (size_t)b * 1024 + tid * 4);
        *(f32x4*)&sm.u.pq.h[tid * 4] = v;
      }
      __syncthreads();
      int o = tid >> 6, lane = tid & 63;
      int d = (wg & 15) * 8 + o;
      double a = 0.0;
#pragma unroll
      for (int k = 0; k < 16; ++k) {
        int c = lane + 64 * k;
        a += (double)W_q[(size_t)d * 1024 + c] * (double)sm.u.pq.h[c];
      }
#pragma unroll
      for (int m = 1; m <= 32; m <<= 1) a += __shfl_xor(a, m);
      if (lane == 0) astoref(qf + b * 128 + d, (float)a);
    }
    gridbar(barmem, lgen, wg, tid);

    // ================= P_att : energies =================
    {
      int b = wg >> 4, t0 = (wg & 15) * 32;
      if (tid < 62) {
        int g = t0 - 15 + tid;
        sm.u.att.cum[tid] = (g >= 0 && g < TE) ? ntload1d(cumg + b * TE + g) : 0.0;
      } else if (tid < 190) {
        sm.u.att.q[tid - 62] = (double)ntload1f(qf + b * 128 + (tid - 62));
      }
      __syncthreads();
#pragma unroll
      for (int it = 0; it < 2; ++it) {
        int task = tid + it * NTH;
        int t = task >> 5, ch = task & 31;
        double v = sm.blc[ch];
#pragma unroll
        for (int k = 0; k < 31; ++k) v += (double)sm.wcl[ch * 31 + k] * sm.u.att.cum[t + k];
        sm.u.att.loc[t][ch] = v;
      }
      __syncthreads();
      int t = tid >> 4, part = tid & 15;
      double en = 0.0;
      for (int k = 0; k < 8; ++k) {
        int d = part + 16 * k;
        double sv = sm.u.att.q[d] + sm.bld[d] +
                    (double)procTf[((size_t)(b * 128 + d)) * TE + t0 + t];
#pragma unroll
        for (int c = 0; c < 32; ++c)
          sv += sm.u.att.loc[t][c] * (double)sm.wldT[c * 128 + d];
        en += tanh(sv) * sm.we[d];
      }
#pragma unroll
      for (int m = 1; m <= 8; m <<= 1) en += __shfl_xor(en, m);
      if (part == 0) astoref(ef + b * TE + t0 + t, (float)(en + sm.be0));
    }
    gridbar(barmem, lgen, wg, tid);

    // ================= P_soft : softmax over t + cum update =================
    if (wg < 16) {
      int b = wg;
      double e = (double)ntload1f(ef + b * TE + tid);
      double mx = e;
#pragma unroll
      for (int m = 1; m <= 32; m <<= 1) mx = fmax(mx, __shfl_xor(mx, m));
      if ((tid & 63) == 0) sm.u.soft.red[tid >> 6] = mx;
      __syncthreads();
      if (tid == 0) {
        double mm = sm.u.soft.red[0];
        for (int i = 1; i < 8; ++i) mm = fmax(mm, sm.u.soft.red[i]);
        sm.u.soft.red[0] = mm;
      }
      __syncthreads();
      double p = exp(e - sm.u.soft.red[0]);
      __syncthreads();
      double ssum = p;
#pragma unroll
      for (int m = 1; m <= 32; m <<= 1) ssum += __shfl_xor(ssum, m);
      if ((tid & 63) == 0) sm.u.soft.red[tid >> 6] = ssum;
      __syncthreads();
      if (tid == 0) {
        double t_ = 0.0;
        for (int i = 0; i < 8; ++i) t_ += sm.u.soft.red[i];
        sm.u.soft.red[0] = 1.0 / t_;
      }
      __syncthreads();
      double a = p * sm.u.soft.red[0];
      astoref(awf + b * TE + tid, (float)a);
      astored(cumg + b * TE + tid, ntload1d(cumg + b * TE + tid) + a);
    }
    gridbar(barmem, lgen, wg, tid);

    // ================= P_ctx : ctx[b] = aw . inputs[b] =================
    {
      int b = wg >> 4, e0 = (wg & 15) * 32;
      sm.u.ctxp.aw[tid] = ntload1f(awf + b * TE + tid);
      __syncthreads();
      int e = e0 + (tid & 31), tp = tid >> 5;
      double a = 0.0;
      for (int t = tp * 32; t < tp * 32 + 32; ++t)
        a += (double)sm.u.ctxp.aw[t] * (double)inputs[((size_t)(b * TE + t)) * EE + e];
      sm.u.ctxp.red[tp][tid & 31] = a;
      __syncthreads();
      if (tid < 32) {
        double v = 0.0;
        for (int j = 0; j < 16; ++j) v += sm.u.ctxp.red[j][tid];
        astoref(ctxf + b * EE + e0 + tid, (float)v);
      }
    }
    gridbar(barmem, lgen, wg, tid);

    // ================= P_out (fixed b per WG) + g1pre(s+1) =================
    {
      int b = wg & 15, obase = wg >> 4;
      if (tid < 256) {
        f32x4 v = ntload4(h_allf + (size_t)b * 1024 + tid * 4);
        *(f32x4*)&sm.u.outp.hb[tid * 4] = v;
      } else if (tid < 384) {
        f32x4 v = ntload4(ctxf + b * EE + (tid - 256) * 4);
        *(f32x4*)&sm.u.outp.hb[1024 + (tid - 256) * 4] = v;
      }
      __syncthreads();
      for (int j = 0; j < 6; ++j) {
        int o = obase + 16 * j;      // 0..95; valid when o <= 80
        if (o <= NM) {
          const float* wr = (o < NM) ? (W_proj + (size_t)o * 1536) : W_stop;
          double a = 0.0;
#pragma unroll
          for (int kk = 0; kk < 3; ++kk) {
            int k = tid + kk * NTH;
            a += (double)wr[k] * (double)sm.u.outp.hb[k];
          }
#pragma unroll
          for (int m = 1; m <= 32; m <<= 1) a += __shfl_xor(a, m);
          if ((tid & 63) == 0) sm.u.outp.red[tid >> 6] = a;
          __syncthreads();
          if (tid == 0) {
            double v = 0.0;
            for (int i = 0; i < 8; ++i) v += sm.u.outp.red[i];
            v += (o < NM) ? (double)b_proj[o] : (double)b_stop[0];
            if (o < NM) astoref(out + ((size_t)b * TD + s) * NM + o, (float)v);
            else        astoref(out + (size_t)NB * TD * NM + b * TD + s, (float)v);
          }
          __syncthreads();
        }
      }
      __syncthreads();
      if (s < TD - 1) {
        const int ss = s + 1;
        for (int j = 0; j < 4; ++j) {
          f32x4 v = ntload4(ctxf + (tid + j * NTH) * 4);
          *(f32x4*)&sm.u.g1p.ctxall[(tid + j * NTH) * 4] = v;
        }
        __syncthreads();
        for (int b2 = 0; b2 < 16; ++b2) {
          double a = 0.0;
#pragma unroll
          for (int k = 0; k < 8; ++k)
            a += (double)wD[k] * (double)p_allf[((size_t)ss * 16 + b2) * 256 + l + 32 * k];
#pragma unroll
          for (int k = 8; k < 24; ++k)
            a += (double)wD[k] * (double)sm.u.g1p.ctxall[b2 * 512 + l + 32 * k - 256];
#pragma unroll
          for (int m = 1; m <= 16; m <<= 1) a += __shfl_xor(a, m);
          if (l == 0) sm.g1l[b2][q] = a + sm.b1l[q];
        }
        __syncthreads();
        if (tid < 4) astoref(h1f + 1024 + wg * 4 + tid, 0.f);
        else if (tid < 8) astoref(h2f + 1024 + wg * 4 + (tid - 4), 0.f);
      }
    }
    gridbar(barmem, lgen, wg, tid);
  }
}

extern "C" void kernel_launch(void* const* d_in, const int* in_sizes, int n_in,
                              void* d_out, int out_size, void* d_ws, size_t ws_size,
                              hipStream_t stream) {
  const float* inputs = (const float*)d_in[0];
  const float* pmels  = (const float*)d_in[1];
  const float* W_enc  = (const float*)d_in[2];
  const float* W_q    = (const float*)d_in[3];
  const float* W_lc   = (const float*)d_in[4];
  const float* b_lc   = (const float*)d_in[5];
  const float* W_ld   = (const float*)d_in[6];
  const float* b_ld   = (const float*)d_in[7];
  const float* w_e    = (const float*)d_in[8];
  const float* b_e    = (const float*)d_in[9];
  const float* W_p1   = (const float*)d_in[10];
  const float* W_p2   = (const float*)d_in[11];
  const float* W_ih1  = (const float*)d_in[12];
  const float* W_hh1  = (const float*)d_in[13];
  const float* b_ih1  = (const float*)d_in[14];
  const float* b_hh1  = (const float*)d_in[15];
  const float* W_ih2  = (const float*)d_in[16];
  const float* W_hh2  = (const float*)d_in[17];
  const float* b_ih2  = (const float*)d_in[18];
  const float* b_hh2  = (const float*)d_in[19];
  const float* W_proj = (const float*)d_in[20];
  const float* b_proj = (const float*)d_in[21];
  const float* W_stop = (const float*)d_in[22];
  const float* b_stop = (const float*)d_in[23];
  float* out = (float*)d_out;

  float* ws     = (float*)d_ws;
  float* p_allf = ws;                   // 524288 f
  float* procTf = p_allf + 524288;      // 1048576 f
  float* h1f    = procTf + 1048576;     // 2048 f (2 parity slots)
  float* h2f    = h1f + 2048;           // 2048 f
  float* h_allf = h2f + 2048;           // 16384 f
  float* qf     = h_allf + 16384;       // 2048 f
  float* ef     = qf + 2048;            // 8192 f
  float* awf    = ef + 8192;            // 8192 f
  float* ctxf   = awf + 8192;           // 8192 f
  double* cumg  = (double*)(ctxf + 8192);        // 8192 d
  uint32_t* barmem = (uint32_t*)(cumg + 8192);   // 8192 u32 (flags + releases)

  // fold_in keys on host: key(42) = (0,42); fold_in data 0 / 1
  uint32_t k1a = 0u, k1b = 0u, k2a = 0u, k2b = 1u;
  threefry2x32(0u, 42u, k1a, k1b);
  threefry2x32(0u, 42u, k2a, k2b);

  k_proc_enc<<<512, 128, 0, stream>>>(inputs, W_enc, procTf);
  k_p<<<TD * NB, 256, 0, stream>>>(pmels, W_p1, W_p2, k1a, k1b, k2a, k2b, p_allf);
  k_init<<<1, 256, 0, stream>>>(cumg, ctxf, h1f, h2f, barmem);

  k_persist<<<NWG, NTH, 0, stream>>>(
      inputs, W_q, W_lc, b_lc, W_ld, b_ld, w_e, b_e,
      W_ih1, W_hh1, b_ih1, b_hh1, W_ih2, W_hh2, b_ih2, b_hh2,
      W_proj, b_proj, W_stop, b_stop,
      p_allf, procTf, h1f, h2f, h_allf, qf, ef, awf, cumg, ctxf,
      barmem, out);

  (void)in_sizes; (void)n_in; (void)out_size; (void)ws_size;
}

// Round 14
// 32174.356 us; speedup vs baseline: 1.3024x; 1.0505x over previous
//
#include <hip/hip_runtime.h>
#include <hip/hip_bf16.h>
#include <stdint.h>

#define TD 128   // decoder steps
#define NB 16    // batch
#define TE 512   // encoder time
#define EE 512   // encoder dim
#define HH 1024  // hidden
#define NM 80    // mel bins
#define PP 256   // prenet dim
#define NWG 256
#define NTH 512

#define AGENT __HIP_MEMORY_SCOPE_AGENT

typedef float f32x4 __attribute__((ext_vector_type(4)));

// ---- WRITE path: agent-scope relaxed (write-through to coherence point) ----
__device__ inline void astoref(float* p, float v) {
  __hip_atomic_store(p, v, __ATOMIC_RELAXED, AGENT);
}
__device__ inline void astored(double* p, double v) {
  __hip_atomic_store(p, v, __ATOMIC_RELAXED, AGENT);
}
// ---- READ path: sc0-only loads — L1 bypass, L2 hit allowed. Freshness:  ----
// ONE captain per XCD invalidates L1+L2 per barrier (agent acquire), then
// siblings' sc0 reads refill L2 once per XCD and the rest hit locally.
__device__ inline f32x4 ntload4(const float* p) {
  f32x4 r;
  asm volatile("global_load_dwordx4 %0, %1, off sc0\n\ts_waitcnt vmcnt(0)"
               : "=&v"(r) : "v"(p) : "memory");
  return r;
}
__device__ inline float ntload1f(const float* p) {
  float r;
  asm volatile("global_load_dword %0, %1, off sc0\n\ts_waitcnt vmcnt(0)"
               : "=&v"(r) : "v"(p) : "memory");
  return r;
}
__device__ inline double ntload1d(const double* p) {
  double r;
  asm volatile("global_load_dwordx2 %0, %1, off sc0\n\ts_waitcnt vmcnt(0)"
               : "=&v"(r) : "v"(p) : "memory");
  return r;
}
__device__ inline double dsig(double x) { return 1.0 / (1.0 + exp(-x)); }

// ---------------- Threefry-2x32 (exact JAX schedule) ----------------
__host__ __device__ inline void threefry2x32(uint32_t k0, uint32_t k1,
                                             uint32_t& x0, uint32_t& x1) {
  uint32_t ks0 = k0, ks1 = k1, ks2 = k0 ^ k1 ^ 0x1BD11BDAu;
  x0 += ks0; x1 += ks1;
#define RND(rot) { x0 += x1; x1 = (x1 << (rot)) | (x1 >> (32 - (rot))); x1 ^= x0; }
  RND(13) RND(15) RND(26) RND(6)
  x0 += ks1; x1 += ks2 + 1u;
  RND(17) RND(29) RND(16) RND(24)
  x0 += ks2; x1 += ks0 + 2u;
  RND(13) RND(15) RND(26) RND(6)
  x0 += ks0; x1 += ks1 + 3u;
  RND(17) RND(29) RND(16) RND(24)
  x0 += ks1; x1 += ks2 + 4u;
  RND(13) RND(15) RND(26) RND(6)
  x0 += ks2; x1 += ks0 + 5u;
#undef RND
}

// JAX partitionable threefry random_bits, bit_width=32: bits = out0 ^ out1.
__device__ inline double mask_val(uint32_t ka, uint32_t kb, uint32_t i) {
  uint32_t x0 = 0u, x1 = i;
  threefry2x32(ka, kb, x0, x1);
  uint32_t bits = x0 ^ x1;
  float u = __uint_as_float((bits >> 9) | 0x3f800000u) - 1.0f;
  return (u < 0.5f) ? 2.0 : 0.0;
}

// ---------------- precompute: proc_enc (transposed [b][d][t], fp64->f32) ----------------
__global__ void k_proc_enc(const float* __restrict__ inputs,
                           const float* __restrict__ W_enc,
                           float* __restrict__ procTf) {
  int blk = blockIdx.x;          // 512 = 16 b * 32 t-tiles
  int b = blk >> 5;
  int t0 = (blk & 31) * 16;
  int d = threadIdx.x;           // 128
  __shared__ float in_l[16][EE];
  for (int idx = threadIdx.x; idx < 16 * EE; idx += blockDim.x) {
    int tt = idx >> 9, e = idx & 511;
    in_l[tt][e] = inputs[((size_t)(b * TE + t0 + tt)) * EE + e];
  }
  __syncthreads();
  double acc[16];
#pragma unroll
  for (int tt = 0; tt < 16; ++tt) acc[tt] = 0.0;
  const float* wr = W_enc + (size_t)d * EE;
  for (int e = 0; e < EE; ++e) {
    double w = (double)wr[e];
#pragma unroll
    for (int tt = 0; tt < 16; ++tt) acc[tt] += w * (double)in_l[tt][e];
  }
  for (int tt = 0; tt < 16; ++tt)
    procTf[((size_t)(b * 128 + d)) * TE + t0 + tt] = (float)acc[tt];
}

// ---------------- precompute: prenet p for all (s,b), masks inline ----------------
__global__ void k_p(const float* __restrict__ pm, const float* __restrict__ Wp1,
                    const float* __restrict__ Wp2,
                    uint32_t k1a, uint32_t k1b, uint32_t k2a, uint32_t k2b,
                    float* __restrict__ p_allf) {
  int sb = blockIdx.x;           // s*16+b, 2048 blocks
  int s = sb >> 4, b = sb & 15;
  int tid = threadIdx.x;         // 256
  uint32_t mi = (uint32_t)(sb * PP + tid);
  double d1 = mask_val(k1a, k1b, mi);
  double d2 = mask_val(k2a, k2b, mi);
  __shared__ float x_l[NM];
  __shared__ double p1_l[PP];
  if (tid < NM) x_l[tid] = (s == 0) ? 0.f : pm[(b * NM + tid) * TD + (s - 1)];
  __syncthreads();
  double a = 0.0;
  const float* w1 = Wp1 + tid * NM;
  for (int m = 0; m < NM; ++m) a += (double)w1[m] * (double)x_l[m];
  a = fmax(a, 0.0) * d1;
  p1_l[tid] = a;
  __syncthreads();
  double c = 0.0;
  const float* w2 = Wp2 + tid * PP;
  for (int k = 0; k < PP; ++k) c += (double)w2[k] * p1_l[k];
  c = fmax(c, 0.0) * d2;
  p_allf[sb * PP + tid] = (float)c;
}

// ---------------- init: zero persistent state + barrier memory ----------------
__global__ void k_init(double* __restrict__ cumg, float* __restrict__ ctxf,
                       float* __restrict__ h1f, float* __restrict__ h2f,
                       uint32_t* __restrict__ barmem) {
  int tid = threadIdx.x;
  for (int i = tid; i < NB * TE; i += 256) cumg[i] = 0.0;
  for (int i = tid; i < NB * EE; i += 256) ctxf[i] = 0.f;
  for (int i = tid; i < 2 * HH; i += 256) { h1f[i] = 0.f; h2f[i] = 0.f; }
  for (int i = tid; i < 8704; i += 256) barmem[i] = 0u;
}

// ---------------- persistent LDS layout ----------------
struct SMEM {
  float wldT[4096];            // wldT[c*128+d] = W_ld[d*32+c]
  float wcl[992];
  double bld[128], we[128], blc[32];
  double b1l[16], b2l[16];
  double g1l[16][16];          // g1pre per item per owned-row
  double gA[16], gBC[16];
  double c1l[4], c2l[4];
  double be0;
  int myg, iscap;
  union U {
    struct { float h1[1024], h2[1024]; } cell;            // 8 KB
    struct { float h[1024]; } pq;                          // 4 KB
    struct { float ctxall[8192]; } g1p;                    // 32 KB
    struct { double cum[64], q[128], loc[32][33]; } att;   // ~14 KB
    struct { float aw[512]; double red[16][32]; } ctxp;    // 6.1 KB
    struct { double red[16]; } soft;
    struct { float hb[1536]; double red[16]; } outp;       // 6.3 KB
  } u;
};

// barmem layout (u32 idx): arrivals wg*16 (0..4095); releases 4096+wg*16;
// inv_done 8192+g*16 (g<8); xcd table 8320+wg (256 entries).

// Setup barrier (no invalidation) — used once before groups are known.
__device__ inline void gridbar0(uint32_t* barmem, uint32_t& lgen, int wg, int tid) {
  __syncthreads();
  lgen++;
  if (wg == 0) {
    if (tid >= 256 && tid < 511) {
      const uint32_t* fl = &barmem[(tid - 255) * 16];
      while (__hip_atomic_load(fl, __ATOMIC_RELAXED, AGENT) < lgen)
        __builtin_amdgcn_s_sleep(1);
    }
    __syncthreads();
    if (tid < 256) {
      asm volatile("s_waitcnt vmcnt(0)" ::: "memory");
      __hip_atomic_store(&barmem[4096 + tid * 16], lgen, __ATOMIC_RELAXED, AGENT);
    }
  } else {
    if (tid == 0) {
      __hip_atomic_store(&barmem[wg * 16], lgen, __ATOMIC_RELAXED, AGENT);
      while (__hip_atomic_load(&barmem[4096 + wg * 16], __ATOMIC_RELAXED, AGENT) < lgen)
        __builtin_amdgcn_s_sleep(1);
    }
  }
  __syncthreads();
}

// Main barrier: replicated flags + per-XCD captain invalidation.
// Captain (one per physical XCD group) performs the agent-ACQUIRE (L1+L2
// invalidate) after observing release, then publishes inv_done[g]; members
// poll inv_done via agent loads (mapping-independent), then their sc0 reads
// refill the XCD L2 once and siblings hit locally.
__device__ inline void gridbar(uint32_t* barmem, uint32_t& lgen, int wg, int tid,
                               int myg, int iscap) {
  __syncthreads();
  lgen++;
  if (wg == 0) {
    if (tid >= 256 && tid < 511) {
      const uint32_t* fl = &barmem[(tid - 255) * 16];
      while (__hip_atomic_load(fl, __ATOMIC_RELAXED, AGENT) < lgen)
        __builtin_amdgcn_s_sleep(1);
    }
    __syncthreads();
    if (tid < 256) {
      asm volatile("s_waitcnt vmcnt(0)" ::: "memory");
      __hip_atomic_store(&barmem[4096 + tid * 16], lgen, __ATOMIC_RELAXED, AGENT);
    }
    if (tid == 0) {    // wg0 is min-wg overall -> captain of its group
      (void)__hip_atomic_load(&barmem[8192 + myg * 16], __ATOMIC_ACQUIRE, AGENT);
      asm volatile("s_waitcnt vmcnt(0)" ::: "memory");
      __hip_atomic_store(&barmem[8192 + myg * 16], lgen, __ATOMIC_RELAXED, AGENT);
    }
  } else {
    if (tid == 0) {
      __hip_atomic_store(&barmem[wg * 16], lgen, __ATOMIC_RELAXED, AGENT);
      while (__hip_atomic_load(&barmem[4096 + wg * 16], __ATOMIC_RELAXED, AGENT) < lgen)
        __builtin_amdgcn_s_sleep(1);
      if (iscap) {
        (void)__hip_atomic_load(&barmem[8192 + myg * 16], __ATOMIC_ACQUIRE, AGENT);
        asm volatile("s_waitcnt vmcnt(0)" ::: "memory");
        __hip_atomic_store(&barmem[8192 + myg * 16], lgen, __ATOMIC_RELAXED, AGENT);
      } else {
        while (__hip_atomic_load(&barmem[8192 + myg * 16], __ATOMIC_RELAXED, AGENT) < lgen)
          __builtin_amdgcn_s_sleep(1);
      }
    }
  }
  __syncthreads();
}

// ---------------- the persistent decoder kernel ----------------
__global__ __launch_bounds__(NTH)
__attribute__((amdgpu_waves_per_eu(2, 2)))
void k_persist(
    const float* __restrict__ inputs,
    const float* __restrict__ W_q,
    const float* __restrict__ W_lc, const float* __restrict__ b_lc,
    const float* __restrict__ W_ld, const float* __restrict__ b_ld,
    const float* __restrict__ w_e, const float* __restrict__ b_e,
    const float* __restrict__ W_ih1, const float* __restrict__ W_hh1,
    const float* __restrict__ b_ih1, const float* __restrict__ b_hh1,
    const float* __restrict__ W_ih2, const float* __restrict__ W_hh2,
    const float* __restrict__ b_ih2, const float* __restrict__ b_hh2,
    const float* __restrict__ W_proj, const float* __restrict__ b_proj,
    const float* __restrict__ W_stop, const float* __restrict__ b_stop,
    const float* __restrict__ p_allf, const float* __restrict__ procTf,
    float* h1f, float* h2f, float* h_allf, float* qf,
    float* ef, float* awf, double* cumg, float* ctxf,
    uint32_t* barmem, float* out) {
  __shared__ SMEM sm;
  const int wg = blockIdx.x, tid = threadIdx.x;
  const int q = tid >> 5, l = tid & 31;       // row-slot 0..15, col-lane 0..31
  const int row = (q >> 2) * 1024 + wg * 4 + (q & 3);  // owned row in 4096
  uint32_t lgen = 0;

  // ---- persistent LDS constants ----
  for (int i = tid; i < 4096; i += NTH) sm.wldT[(i & 31) * 128 + (i >> 5)] = W_ld[i];
  for (int i = tid; i < 992; i += NTH) sm.wcl[i] = W_lc[i];
  for (int i = tid; i < 128; i += NTH) { sm.bld[i] = (double)b_ld[i]; sm.we[i] = (double)w_e[i]; }
  if (tid < 32) sm.blc[tid] = (double)b_lc[tid];
  if (tid == 0) sm.be0 = (double)b_e[0];
  if (l == 0) {
    sm.b1l[q] = (double)b_ih1[row] + (double)b_hh1[row];
    sm.b2l[q] = (double)b_ih2[row] + (double)b_hh2[row];
  }

  // ---- register-resident weights (120 regs, pinned) ----
  float wA[32], wB[32], wC[32], wD[24];
#pragma unroll
  for (int k = 0; k < 32; ++k) {
    int c = l + 32 * k;
    wA[k] = W_hh1[(size_t)row * 1024 + c];
    wB[k] = W_ih2[(size_t)row * 1024 + c];
    wC[k] = W_hh2[(size_t)row * 1024 + c];
  }
#pragma unroll
  for (int k = 0; k < 24; ++k) wD[k] = W_ih1[(size_t)row * 768 + l + 32 * k];
#pragma unroll
  for (int k = 0; k < 32; ++k) {
    asm volatile("" : "+v"(wA[k]));
    asm volatile("" : "+v"(wB[k]));
    asm volatile("" : "+v"(wC[k]));
  }
#pragma unroll
  for (int k = 0; k < 24; ++k) asm volatile("" : "+v"(wD[k]));

  // ---- publish physical XCC id ----
  if (tid == 0) {
    // s_getreg_b32 hwreg(HW_REG_XCC_ID=20, offset 0, size 32)
    uint32_t xcc = (uint32_t)__builtin_amdgcn_s_getreg(20 | (31 << 11)) & 7u;
    __hip_atomic_store(&barmem[8320 + wg], xcc, __ATOMIC_RELAXED, AGENT);
    asm volatile("s_waitcnt vmcnt(0)" ::: "memory");
  }
  __syncthreads();

  // ---- prologue part 1: g1pre for step 0 (ctx zeroed by k_init) ----
  {
    for (int j = 0; j < 4; ++j) {
      f32x4 v = ntload4(ctxf + (tid + j * NTH) * 4);
      *(f32x4*)&sm.u.g1p.ctxall[(tid + j * NTH) * 4] = v;
    }
    __syncthreads();
    for (int b = 0; b < 16; ++b) {
      double a = 0.0;
#pragma unroll
      for (int k = 0; k < 8; ++k)
        a += (double)wD[k] * (double)p_allf[((size_t)0 * 16 + b) * 256 + l + 32 * k];
#pragma unroll
      for (int k = 8; k < 24; ++k)
        a += (double)wD[k] * (double)sm.u.g1p.ctxall[b * 512 + l + 32 * k - 256];
#pragma unroll
      for (int m = 1; m <= 16; m <<= 1) a += __shfl_xor(a, m);
      if (l == 0) sm.g1l[b][q] = a + sm.b1l[q];
    }
    __syncthreads();
  }
  gridbar0(barmem, lgen, wg, tid);

  // ---- group/captain election from the snapshot table ----
  if (tid == 0) {
    uint32_t myx = __hip_atomic_load(&barmem[8320 + wg], __ATOMIC_RELAXED, AGENT);
    int cap = 1;
    for (int w = 0; w < wg; ++w) {
      if (__hip_atomic_load(&barmem[8320 + w], __ATOMIC_RELAXED, AGENT) == myx) {
        cap = 0; break;
      }
    }
    sm.myg = (int)myx; sm.iscap = cap;
  }
  __syncthreads();
  const int myg = sm.myg, iscap = sm.iscap;

  for (int s = 0; s < TD; ++s) {
    // ================= 17 pipelined cell rounds =================
    for (int r = 0; r <= 16; ++r) {
      if (r == 0 && tid < 4) { sm.c1l[tid] = 0.0; sm.c2l[tid] = 0.0; }
      // stage h1(r-1) [slot (r&1)^1] and h2(r-2) [slot r&1] via sc0 loads
      if (tid < 256) {
        f32x4 v = ntload4(h1f + (((r & 1) ^ 1)) * 1024 + tid * 4);
        *(f32x4*)&sm.u.cell.h1[tid * 4] = v;
      } else if (r > 0) {
        f32x4 v = ntload4(h2f + (r & 1) * 1024 + (tid - 256) * 4);
        *(f32x4*)&sm.u.cell.h2[(tid - 256) * 4] = v;
      }
      __syncthreads();

      double a0 = 0.0, a1 = 0.0, a2 = 0.0;
#pragma unroll
      for (int k = 0; k < 32; ++k) {
        double h1v = (double)sm.u.cell.h1[l + 32 * k];
        a0 += (double)wA[k] * h1v;
        a1 += (double)wB[k] * h1v;
        a2 += (double)wC[k] * (double)sm.u.cell.h2[l + 32 * k];
      }
#pragma unroll
      for (int m = 1; m <= 16; m <<= 1) {
        a0 += __shfl_xor(a0, m);
        a1 += __shfl_xor(a1, m);
        a2 += __shfl_xor(a2, m);
      }
      if (l == 0) { sm.gA[q] = a0; sm.gBC[q] = a1 + a2; }
      __syncthreads();

      if (r < 16 && tid < 4) {          // cell1(item r)
        int jj = tid;
        double gi = sm.g1l[r][jj]      + sm.gA[jj];
        double gf = sm.g1l[r][4 + jj]  + sm.gA[4 + jj];
        double gg = sm.g1l[r][8 + jj]  + sm.gA[8 + jj];
        double go = sm.g1l[r][12 + jj] + sm.gA[12 + jj];
        double cn = dsig(gf) * sm.c1l[jj] + dsig(gi) * tanh(gg);
        double hn = dsig(go) * tanh(cn);
        sm.c1l[jj] = cn;
        astoref(h1f + (r & 1) * 1024 + wg * 4 + jj, (float)hn);
      }
      if (r > 0 && tid >= 8 && tid < 12) {  // cell2(item r-1)
        int jj = tid - 8, b = r - 1;
        double gi = sm.gBC[jj]      + sm.b2l[jj];
        double gf = sm.gBC[4 + jj]  + sm.b2l[4 + jj];
        double gg = sm.gBC[8 + jj]  + sm.b2l[8 + jj];
        double go = sm.gBC[12 + jj] + sm.b2l[12 + jj];
        double cn = dsig(gf) * sm.c2l[jj] + dsig(gi) * tanh(gg);
        double hn = dsig(go) * tanh(cn);
        sm.c2l[jj] = cn;
        astoref(h2f + ((b & 1)) * 1024 + wg * 4 + jj, (float)hn);
        astoref(h_allf + (size_t)b * 1024 + wg * 4 + jj, (float)hn);
      }
      gridbar(barmem, lgen, wg, tid, myg, iscap);
    }

    // ================= P_q : q[b][d] = Wq . h_all[b] =================
    {
      int b = wg >> 4;
      if (tid < 256) {
        f32x4 v = ntload4(h_allf + (size_t)b * 1024 + tid * 4);
        *(f32x4*)&sm.u.pq.h[tid * 4] = v;
      }
      __syncthreads();
      int o = tid >> 6, lane = tid & 63;
      int d = (wg & 15) * 8 + o;
      double a = 0.0;
#pragma unroll
      for (int k = 0; k < 16; ++k) {
        int c = lane + 64 * k;
        a += (double)W_q[(size_t)d * 1024 + c] * (double)sm.u.pq.h[c];
      }
#pragma unroll
      for (int m = 1; m <= 32; m <<= 1) a += __shfl_xor(a, m);
      if (lane == 0) astoref(qf + b * 128 + d, (float)a);
    }
    gridbar(barmem, lgen, wg, tid, myg, iscap);

    // ================= P_att : energies =================
    {
      int b = wg >> 4, t0 = (wg & 15) * 32;
      if (tid < 62) {
        int g = t0 - 15 + tid;
        sm.u.att.cum[tid] = (g >= 0 && g < TE) ? ntload1d(cumg + b * TE + g) : 0.0;
      } else if (tid < 190) {
        sm.u.att.q[tid - 62] = (double)ntload1f(qf + b * 128 + (tid - 62));
      }
      __syncthreads();
#pragma unroll
      for (int it = 0; it < 2; ++it) {
        int task = tid + it * NTH;
        int t = task >> 5, ch = task & 31;
        double v = sm.blc[ch];
#pragma unroll
        for (int k = 0; k < 31; ++k) v += (double)sm.wcl[ch * 31 + k] * sm.u.att.cum[t + k];
        sm.u.att.loc[t][ch] = v;
      }
      __syncthreads();
      int t = tid >> 4, part = tid & 15;
      double en = 0.0;
      for (int k = 0; k < 8; ++k) {
        int d = part + 16 * k;
        double sv = sm.u.att.q[d] + sm.bld[d] +
                    (double)procTf[((size_t)(b * 128 + d)) * TE + t0 + t];
#pragma unroll
        for (int c = 0; c < 32; ++c)
          sv += sm.u.att.loc[t][c] * (double)sm.wldT[c * 128 + d];
        en += tanh(sv) * sm.we[d];
      }
#pragma unroll
      for (int m = 1; m <= 8; m <<= 1) en += __shfl_xor(en, m);
      if (part == 0) astoref(ef + b * TE + t0 + t, (float)(en + sm.be0));
    }
    gridbar(barmem, lgen, wg, tid, myg, iscap);

    // ================= P_soft : softmax over t + cum update =================
    if (wg < 16) {
      int b = wg;
      double e = (double)ntload1f(ef + b * TE + tid);
      double mx = e;
#pragma unroll
      for (int m = 1; m <= 32; m <<= 1) mx = fmax(mx, __shfl_xor(mx, m));
      if ((tid & 63) == 0) sm.u.soft.red[tid >> 6] = mx;
      __syncthreads();
      if (tid == 0) {
        double mm = sm.u.soft.red[0];
        for (int i = 1; i < 8; ++i) mm = fmax(mm, sm.u.soft.red[i]);
        sm.u.soft.red[0] = mm;
      }
      __syncthreads();
      double p = exp(e - sm.u.soft.red[0]);
      __syncthreads();
      double ssum = p;
#pragma unroll
      for (int m = 1; m <= 32; m <<= 1) ssum += __shfl_xor(ssum, m);
      if ((tid & 63) == 0) sm.u.soft.red[tid >> 6] = ssum;
      __syncthreads();
      if (tid == 0) {
        double t_ = 0.0;
        for (int i = 0; i < 8; ++i) t_ += sm.u.soft.red[i];
        sm.u.soft.red[0] = 1.0 / t_;
      }
      __syncthreads();
      double a = p * sm.u.soft.red[0];
      astoref(awf + b * TE + tid, (float)a);
      astored(cumg + b * TE + tid, ntload1d(cumg + b * TE + tid) + a);
    }
    gridbar(barmem, lgen, wg, tid, myg, iscap);

    // ================= P_ctx : ctx[b] = aw . inputs[b] =================
    {
      int b = wg >> 4, e0 = (wg & 15) * 32;
      sm.u.ctxp.aw[tid] = ntload1f(awf + b * TE + tid);
      __syncthreads();
      int e = e0 + (tid & 31), tp = tid >> 5;
      double a = 0.0;
      for (int t = tp * 32; t < tp * 32 + 32; ++t)
        a += (double)sm.u.ctxp.aw[t] * (double)inputs[((size_t)(b * TE + t)) * EE + e];
      sm.u.ctxp.red[tp][tid & 31] = a;
      __syncthreads();
      if (tid < 32) {
        double v = 0.0;
        for (int j = 0; j < 16; ++j) v += sm.u.ctxp.red[j][tid];
        astoref(ctxf + b * EE + e0 + tid, (float)v);
      }
    }
    gridbar(barmem, lgen, wg, tid, myg, iscap);

    // ================= P_out (fixed b per WG) + g1pre(s+1) =================
    {
      int b = wg & 15, obase = wg >> 4;
      if (tid < 256) {
        f32x4 v = ntload4(h_allf + (size_t)b * 1024 + tid * 4);
        *(f32x4*)&sm.u.outp.hb[tid * 4] = v;
      } else if (tid < 384) {
        f32x4 v = ntload4(ctxf + b * EE + (tid - 256) * 4);
        *(f32x4*)&sm.u.outp.hb[1024 + (tid - 256) * 4] = v;
      }
      __syncthreads();
      for (int j = 0; j < 6; ++j) {
        int o = obase + 16 * j;      // 0..95; valid when o <= 80
        if (o <= NM) {
          const float* wr = (o < NM) ? (W_proj + (size_t)o * 1536) : W_stop;
          double a = 0.0;
#pragma unroll
          for (int kk = 0; kk < 3; ++kk) {
            int k = tid + kk * NTH;
            a += (double)wr[k] * (double)sm.u.outp.hb[k];
          }
#pragma unroll
          for (int m = 1; m <= 32; m <<= 1) a += __shfl_xor(a, m);
          if ((tid & 63) == 0) sm.u.outp.red[tid >> 6] = a;
          __syncthreads();
          if (tid == 0) {
            double v = 0.0;
            for (int i = 0; i < 8; ++i) v += sm.u.outp.red[i];
            v += (o < NM) ? (double)b_proj[o] : (double)b_stop[0];
            if (o < NM) astoref(out + ((size_t)b * TD + s) * NM + o, (float)v);
            else        astoref(out + (size_t)NB * TD * NM + b * TD + s, (float)v);
          }
          __syncthreads();
        }
      }
      __syncthreads();
      if (s < TD - 1) {
        const int ss = s + 1;
        for (int j = 0; j < 4; ++j) {
          f32x4 v = ntload4(ctxf + (tid + j * NTH) * 4);
          *(f32x4*)&sm.u.g1p.ctxall[(tid + j * NTH) * 4] = v;
        }
        __syncthreads();
        for (int b2 = 0; b2 < 16; ++b2) {
          double a = 0.0;
#pragma unroll
          for (int k = 0; k < 8; ++k)
            a += (double)wD[k] * (double)p_allf[((size_t)ss * 16 + b2) * 256 + l + 32 * k];
#pragma unroll
          for (int k = 8; k < 24; ++k)
            a += (double)wD[k] * (double)sm.u.g1p.ctxall[b2 * 512 + l + 32 * k - 256];
#pragma unroll
          for (int m = 1; m <= 16; m <<= 1) a += __shfl_xor(a, m);
          if (l == 0) sm.g1l[b2][q] = a + sm.b1l[q];
        }
        __syncthreads();
        if (tid < 4) astoref(h1f + 1024 + wg * 4 + tid, 0.f);
        else if (tid < 8) astoref(h2f + 1024 + wg * 4 + (tid - 4), 0.f);
      }
    }
    gridbar(barmem, lgen, wg, tid, myg, iscap);
  }
}

extern "C" void kernel_launch(void* const* d_in, const int* in_sizes, int n_in,
                              void* d_out, int out_size, void* d_ws, size_t ws_size,
                              hipStream_t stream) {
  const float* inputs = (const float*)d_in[0];
  const float* pmels  = (const float*)d_in[1];
  const float* W_enc  = (const float*)d_in[2];
  const float* W_q    = (const float*)d_in[3];
  const float* W_lc   = (const float*)d_in[4];
  const float* b_lc   = (const float*)d_in[5];
  const float* W_ld   = (const float*)d_in[6];
  const float* b_ld   = (const float*)d_in[7];
  const float* w_e    = (const float*)d_in[8];
  const float* b_e    = (const float*)d_in[9];
  const float* W_p1   = (const float*)d_in[10];
  const float* W_p2   = (const float*)d_in[11];
  const float* W_ih1  = (const float*)d_in[12];
  const float* W_hh1  = (const float*)d_in[13];
  const float* b_ih1  = (const float*)d_in[14];
  const float* b_hh1  = (const float*)d_in[15];
  const float* W_ih2  = (const float*)d_in[16];
  const float* W_hh2  = (const float*)d_in[17];
  const float* b_ih2  = (const float*)d_in[18];
  const float* b_hh2  = (const float*)d_in[19];
  const float* W_proj = (const float*)d_in[20];
  const float* b_proj = (const float*)d_in[21];
  const float* W_stop = (const float*)d_in[22];
  const float* b_stop = (const float*)d_in[23];
  float* out = (float*)d_out;

  float* ws     = (float*)d_ws;
  float* p_allf = ws;                   // 524288 f
  float* procTf = p_allf + 524288;      // 1048576 f
  float* h1f    = procTf + 1048576;     // 2048 f (2 parity slots)
  float* h2f    = h1f + 2048;           // 2048 f
  float* h_allf = h2f + 2048;           // 16384 f
  float* qf     = h_allf + 16384;       // 2048 f
  float* ef     = qf + 2048;            // 8192 f
  float* awf    = ef + 8192;            // 8192 f
  float* ctxf   = awf + 8192;           // 8192 f
  double* cumg  = (double*)(ctxf + 8192);        // 8192 d
  uint32_t* barmem = (uint32_t*)(cumg + 8192);   // 8704 u32

  // fold_in keys on host: key(42) = (0,42); fold_in data 0 / 1
  uint32_t k1a = 0u, k1b = 0u, k2a = 0u, k2b = 1u;
  threefry2x32(0u, 42u, k1a, k1b);
  threefry2x32(0u, 42u, k2a, k2b);

  k_proc_enc<<<512, 128, 0, stream>>>(inputs, W_enc, procTf);
  k_p<<<TD * NB, 256, 0, stream>>>(pmels, W_p1, W_p2, k1a, k1b, k2a, k2b, p_allf);
  k_init<<<1, 256, 0, stream>>>(cumg, ctxf, h1f, h2f, barmem);

  k_persist<<<NWG, NTH, 0, stream>>>(
      inputs, W_q, W_lc, b_lc, W_ld, b_ld, w_e, b_e,
      W_ih1, W_hh1, b_ih1, b_hh1, W_ih2, W_hh2, b_ih2, b_hh2,
      W_proj, b_proj, W_stop, b_stop,
      p_allf, procTf, h1f, h2f, h_allf, qf, ef, awf, cumg, ctxf,
      barmem, out);

  (void)in_sizes; (void)n_in; (void)out_size; (void)ws_size;
}